// Round 16
// baseline (346.622 us; speedup 1.0000x reference)
//
#include <hip/hip_runtime.h>
#include <hip/hip_fp16.h>

typedef unsigned long long u64;
typedef __attribute__((ext_vector_type(2))) int i32x2;

#define HH 1024
#define WP 512                     // pairs per image row
#define TPB 512
#define NTX 16
#define NTY 16
#define NBLK (NTX * NTY)           // 256 blocks = 1/CU
#define SR 68                      // staged rows  (64 own + 2 ghost each side)
#define SP 34                      // staged pairs (32 own + 1 ghost each side)
#define NCELL (SR * SP)            // 2312
#define NSYNC 50                   // 2 Jacobi steps per sync
#define BOUNDARY_F 0.1f
#define TOKEN 0x5A5A5A5Au
#define FLAGS_N (NSYNC * NBLK)

union h2u { __half2 h; int i; };

__device__ __forceinline__ i32x2 pack4(float4 v) {     // fp32x4 -> fp16x4 (RNE)
    h2u a, b;
    a.h = __float22half2_rn(make_float2(v.x, v.y));
    b.h = __float22half2_rn(make_float2(v.z, v.w));
    i32x2 r; r.x = a.i; r.y = b.i;
    return r;
}
__device__ __forceinline__ float4 unpack4u(u64 p) {
    h2u a, b; a.i = (int)(unsigned)p; b.i = (int)(unsigned)(p >> 32);
    float2 lo = __half22float2(a.h);
    float2 hi = __half22float2(b.h);
    return make_float4(lo.x, lo.y, hi.x, hi.y);
}

// coherent 8B load (compiler-managed waitcnt -> hazard-safe)
__device__ __forceinline__ u64 cld(const u64* p) {
    return __hip_atomic_load(p, __ATOMIC_RELAXED, __HIP_MEMORY_SCOPE_AGENT);
}
// coherent 8B store: single fabric transaction, bypasses non-coherent L2
__device__ __forceinline__ void cst8(i32x2* base, int elem, i32x2 val) {
    asm volatile("global_store_dwordx2 %0, %1, %2 sc0 sc1"
                 :: "v"(elem * 8), "v"(val), "s"(base) : "memory");
}
__device__ __forceinline__ void waitvm0() {
    asm volatile("s_waitcnt vmcnt(0)" ::: "memory");
}

__device__ __forceinline__ float wfun(float c, float n, float valid) {
    float same = ((c > BOUNDARY_F) != (n > BOUNDARY_F)) ? 1.0f : 0.0f;
    return valid * __expf(-fabsf(c - n + same));
}

__device__ __forceinline__ float4 upd2(float4 c0, float4 c1, unsigned char m,
                                       float4 xc, float4 xu, float4 xd,
                                       float2 xl, float2 xr) {
    float4 o;
    o.x = c0.x*xu.x + c0.y*xd.x + c0.z*xl.x + c0.w*xc.z;
    o.y = c0.x*xu.y + c0.y*xd.y + c0.z*xl.y + c0.w*xc.w;
    o.z = c1.x*xu.z + c1.y*xd.z + c1.z*xc.x + c1.w*xr.x;
    o.w = c1.x*xu.w + c1.y*xd.w + c1.z*xc.y + c1.w*xr.y;
    if (m & 1) { o.x = xc.x; o.y = xc.y; }   // absorbing seeds
    if (m & 2) { o.z = xc.z; o.w = xc.w; }
    return o;
}

// zero all flag slots: every launch is self-contained (no poison assumption,
// no stale TOKEN from a previous launch can un-gate the skew protocol)
__global__ void rw_init_kernel(unsigned* __restrict__ flags) {
    int g = blockIdx.x * blockDim.x + threadIdx.x;
    if (g < FLAGS_N) flags[g] = 0u;
}

__launch_bounds__(TPB)
__global__ void rw_persist_kernel(const float* __restrict__ img,
                                  const int* __restrict__ seeds,
                                  float4* __restrict__ out4,   // d_out fp32, final only
                                  u64* __restrict__ parE,      // ws fp16 parity buffers
                                  u64* __restrict__ parO,
                                  unsigned* __restrict__ flags) {
    const int tid = threadIdx.x;
    const int blk = blockIdx.x;
    const int tx = blk & (NTX - 1), ty = blk >> 4;
    const int row0 = ty * 64 - 2;          // global row of staged r=0
    const int pr0  = tx * 32 - 1;          // global pair of staged q=0

    __shared__ float4 xs[SR][SP + 1];      // state tile (+ ring), fp32
    __shared__ float4 cf0s[SR][SP];        // px0 weights (u,d,l,r) normalized
    __shared__ float4 cf1s[SR][SP];        // px1 weights
    __shared__ unsigned char msks[SR][SP + 2];

    // ---- init: cf, masks, x0 for every staged cell (ring included) ----
    {
        const float2* img2 = (const float2*)img;
        const int2* seeds2 = (const int2*)seeds;
        for (int c = tid; c < NCELL; c += TPB) {
            const int r = c / SP, q = c - (c / SP) * SP;
            const int gi = row0 + r;               // true row (may be OOB)
            const int gq = pr0 + q;                // true pair (may be OOB)
            const int ci = min(max(gi, 0), HH - 1);
            const int cq = min(max(gq, 0), WP - 1);
            const int gj = 2 * gq;                 // true px col of px0
            const int P  = ci * WP + cq;
            const int uP = max(ci - 1, 0) * WP + cq;
            const int dP = min(ci + 1, HH - 1) * WP + cq;

            float2 cc = img2[P], iu = img2[uP], id = img2[dP];
            float il = img[max(2 * P - 1, 0)];
            float ir = img[min(2 * P + 2, HH * 1024 - 1)];
            const float vU = (gi > 0) ? 1.0f : 0.0f;
            const float vD = (gi < HH - 1) ? 1.0f : 0.0f;
            const float vL = (gj > 0) ? 1.0f : 0.0f;
            const float vR = (gj < 1022) ? 1.0f : 0.0f;

            float w0u = wfun(cc.x, iu.x, vU), w0d = wfun(cc.x, id.x, vD);
            float w0l = wfun(cc.x, il, vL),   w0r = wfun(cc.x, cc.y, 1.0f);
            float rs0 = w0u + w0d + w0l + w0r;
            float inv0 = (rs0 > 0.0f) ? 1.0f / rs0 : 0.0f;
            float w1u = wfun(cc.y, iu.y, vU), w1d = wfun(cc.y, id.y, vD);
            float w1l = wfun(cc.y, cc.x, 1.0f), w1r = wfun(cc.y, ir, vR);
            float rs1 = w1u + w1d + w1l + w1r;
            float inv1 = (rs1 > 0.0f) ? 1.0f / rs1 : 0.0f;

            cf0s[r][q] = make_float4(w0u*inv0, w0d*inv0, w0l*inv0, w0r*inv0);
            cf1s[r][q] = make_float4(w1u*inv1, w1d*inv1, w1l*inv1, w1r*inv1);

            int2 s = seeds2[P];
            msks[r][q] = (unsigned char)((s.x > 0 ? 1 : 0) | (s.y > 0 ? 2 : 0));
            xs[r][q] = make_float4((s.x == 1) ? 1.0f : 0.0f,
                                   (s.x == 2) ? 1.0f : 0.0f,
                                   (s.y == 1) ? 1.0f : 0.0f,
                                   (s.y == 2) ? 1.0f : 0.0f);
        }
    }
    __syncthreads();

    // stage-cell mapping for this thread (ring = 264 cells)
    int sr = 0, sq = 0;
    const bool isStager = (tid < 264);
    if (tid < 136) {
        int k = tid / SP;                        // 0..3 -> rows 0,1,66,67
        sr = (k < 2) ? k : 64 + k;
        sq = tid - k * SP;
    } else if (tid < 264) {
        int j = tid - 136;                       // cols q=0,33 for r=2..65
        sr = 2 + (j >> 1);
        sq = (j & 1) * 33;
    }
    const int sgi = min(max(row0 + sr, 0), HH - 1);
    const int sgq = min(max(pr0 + sq, 0), WP - 1);

    for (int m = 0; m < NSYNC; ++m) {
        u64 stg = 0;
        if (m > 0) {
            // ---- poll 8 neighbors' flags: lanes 0..7 of wave 0 ----
            if (tid < 8) {
                const int dy[8] = {-1, 1, 0, 0, -1, -1, 1, 1};
                const int dx[8] = {0, 0, -1, 1, -1, 1, -1, 1};
                int nty = ty + dy[tid], ntx = tx + dx[tid];
                if (nty >= 0 && nty < NTY && ntx >= 0 && ntx < NTX) {
                    const int fi = m * NBLK + nty * NTX + ntx;
                    int guard = 0;
                    while (__hip_atomic_load(&flags[fi], __ATOMIC_RELAXED,
                                             __HIP_MEMORY_SCOPE_AGENT) != TOKEN) {
                        __builtin_amdgcn_s_sleep(1);
                        if (++guard > (1 << 20)) break;
                    }
                }
            }
            __syncthreads();
            asm volatile("" ::: "memory");
            // issue ghost-ring loads (land while we compute interior)
            const u64* pin = (m & 1) ? parO : parE;
            if (isStager) stg = cld(&pin[sgi * WP + sgq]);
        }

        // ---- level 1 interior (A): r 3..64, q 2..31 — own data only ----
        float4 yA[4];
#pragma unroll
        for (int k = 0; k < 4; ++k) {
            int idx = tid + k * TPB;
            if (idx < 1860) {
                int r = 3 + idx / 30, q = 2 + idx % 30;
                float4 xc = xs[r][q];
                float2 xl = make_float2(xs[r][q - 1].z, xs[r][q - 1].w);
                float2 xr = make_float2(xs[r][q + 1].x, xs[r][q + 1].y);
                yA[k] = upd2(cf0s[r][q], cf1s[r][q], msks[r][q],
                             xc, xs[r - 1][q], xs[r + 1][q], xl, xr);
            }
        }
        if (m > 0 && isStager) xs[sr][sq] = unpack4u(stg);
        __syncthreads();                          // ring staged + A regs done

        // ---- level 1 boundary (B): 384 annulus cells ----
        float4 yB;
        int br = 1, bq = 0;
        if (tid < 384) {
            if (tid < 136) {
                int k = tid / SP;                 // rows 1,2,65,66
                br = (k < 2) ? 1 + k : 63 + k;
                bq = tid - k * SP;
            } else {
                int j = tid - 136;                // cols 0,1,32,33 for r=3..64
                br = 3 + (j >> 2);
                const int QT[4] = {0, 1, 32, 33};
                bq = QT[j & 3];
            }
            float4 xc = xs[br][bq];
            float2 xl = (bq > 0) ? make_float2(xs[br][bq - 1].z, xs[br][bq - 1].w)
                                 : make_float2(xc.x, xc.y);
            float2 xr = (bq < SP - 1) ? make_float2(xs[br][bq + 1].x, xs[br][bq + 1].y)
                                      : make_float2(xc.z, xc.w);
            yB = upd2(cf0s[br][bq], cf1s[br][bq], msks[br][bq],
                      xc, xs[br - 1][bq], xs[br + 1][bq], xl, xr);
        }
        __syncthreads();                          // all level-1 reads done

        // ---- write level-1 results (full rect r1..66 × q0..33) ----
#pragma unroll
        for (int k = 0; k < 4; ++k) {
            int idx = tid + k * TPB;
            if (idx < 1860) {
                int r = 3 + idx / 30, q = 2 + idx % 30;
                xs[r][q] = yA[k];
            }
        }
        if (tid < 384) xs[br][bq] = yB;
        __syncthreads();                          // y visible

        // ---- level 2: own cells r 2..65, q 1..32 ----
        float4 o[4];
#pragma unroll
        for (int k = 0; k < 4; ++k) {
            int c = tid + k * TPB;
            int r = 2 + (c >> 5), q = 1 + (c & 31);
            float4 xc = xs[r][q];
            float2 xl = make_float2(xs[r][q - 1].z, xs[r][q - 1].w);
            float2 xr = make_float2(xs[r][q + 1].x, xs[r][q + 1].y);
            o[k] = upd2(cf0s[r][q], cf1s[r][q], msks[r][q],
                        xc, xs[r - 1][q], xs[r + 1][q], xl, xr);
        }

        if (m == NSYNC - 1) {
            // x_100 -> d_out fp32 (never read by any block: race-free)
#pragma unroll
            for (int k = 0; k < 4; ++k) {
                int c = tid + k * TPB;
                int r = 2 + (c >> 5), q = 1 + (c & 31);
                out4[(row0 + r) * WP + (pr0 + q)] = o[k];
            }
            break;
        }

        __syncthreads();                          // level-2 reads of y done
        i32x2* pout = (i32x2*)(((m + 1) & 1) ? parO : parE);
#pragma unroll
        for (int k = 0; k < 4; ++k) {
            int c = tid + k * TPB;
            int r = 2 + (c >> 5), q = 1 + (c & 31);
            xs[r][q] = o[k];
            if (r <= 3 || r >= 64 || q == 1 || q == 32)   // depth-2 boundary ring
                cst8(pout, (row0 + r) * WP + (pr0 + q), pack4(o[k]));
        }
        waitvm0();                                // drain own publishes
        __syncthreads();                          // LDS + all waves drained
        if (tid == 0)
            __hip_atomic_store(&flags[(m + 1) * NBLK + blk], TOKEN,
                               __ATOMIC_RELAXED, __HIP_MEMORY_SCOPE_AGENT);
    }
}

extern "C" void kernel_launch(void* const* d_in, const int* in_sizes, int n_in,
                              void* d_out, int out_size, void* d_ws, size_t ws_size,
                              hipStream_t stream) {
    const float* img = (const float*)d_in[0];
    const int* seeds = (const int*)d_in[1];

    float4* out4 = (float4*)d_out;                              // fp32 final only
    char* ws = (char*)d_ws;
    u64* parE = (u64*)ws;                                       // 4 MB fp16 parity
    u64* parO = (u64*)(ws + 4ull * 1024 * 1024);                // 4 MB fp16 parity
    unsigned* flags = (unsigned*)(ws + 8ull * 1024 * 1024);     // 51.2 KB tokens

    rw_init_kernel<<<(FLAGS_N + 255) / 256, 256, 0, stream>>>(flags);
    rw_persist_kernel<<<NBLK, TPB, 0, stream>>>(img, seeds, out4, parE, parO, flags);
}

// Round 17
// 240.895 us; speedup vs baseline: 1.4389x; 1.4389x over previous
//
#include <hip/hip_runtime.h>
#include <hip/hip_fp16.h>

typedef __attribute__((ext_vector_type(2))) int i32x2;

#define HH 1024
#define ROWP 512                   // pixel-pairs per row
#define NBLK 256                   // 1 block/CU -> co-resident
#define TPB 512
#define NSYNC 50                   // 2 Jacobi steps per sync
#define BOUNDARY_F 0.1f
#define TOKEN 0x5A5A5A5Au
#define FLAGS_N (NSYNC * NBLK)

union h2u { __half2 h; int i; };

__device__ __forceinline__ i32x2 pack4(float4 v) {     // fp32x4 -> fp16x4 (RNE)
    h2u a, b;
    a.h = __float22half2_rn(make_float2(v.x, v.y));
    b.h = __float22half2_rn(make_float2(v.z, v.w));
    i32x2 r; r.x = a.i; r.y = b.i;
    return r;
}
__device__ __forceinline__ float4 unpack4(i32x2 p) {
    h2u a, b; a.i = p.x; b.i = p.y;
    float2 lo = __half22float2(a.h);
    float2 hi = __half22float2(b.h);
    return make_float4(lo.x, lo.y, hi.x, hi.y);
}

// coherent 8B store: single fabric transaction, bypasses non-coherent L2
__device__ __forceinline__ void cst8(i32x2* base, int elem, i32x2 val) {
    asm volatile("global_store_dwordx2 %0, %1, %2 sc0 sc1"
                 :: "v"(elem * 8), "v"(val), "s"(base) : "memory");
}
// coherent 8B load; result MUST be passed through wait4 before any use
__device__ __forceinline__ i32x2 cld8(const i32x2* base, int elem) {
    i32x2 t;
    asm volatile("global_load_dwordx2 %0, %1, %2 sc0 sc1"
                 : "=v"(t) : "v"(elem * 8), "s"(base) : "memory");
    return t;
}
// s_waitcnt with loaded registers as in/out operands: all later uses have a
// data dependency THROUGH the waitcnt (round-12-verified hazard fix).
__device__ __forceinline__ void wait4(i32x2& a, i32x2& b, i32x2& c, i32x2& d) {
    asm volatile("s_waitcnt vmcnt(0)"
                 : "+v"(a), "+v"(b), "+v"(c), "+v"(d) :: "memory");
}
__device__ __forceinline__ void waitvm0() {
    asm volatile("s_waitcnt vmcnt(0)" ::: "memory");
}

__device__ __forceinline__ float wfun(float c, float n, float valid) {
    float same = ((c > BOUNDARY_F) != (n > BOUNDARY_F)) ? 1.0f : 0.0f;
    return valid * __expf(-fabsf(c - n + same));
}

// Jacobi update of one pixel-pair; w = {w0u,w0d,w0l,w0r, w1u,w1d,w1l,w1r}
__device__ __forceinline__ float4 stepr(const float* w, bool m0, bool m1,
                                        float4 xc, float4 xu, float4 xd,
                                        float2 xl, float2 xr) {
    float4 o;
    o.x = w[0]*xu.x + w[1]*xd.x + w[2]*xl.x + w[3]*xc.z;
    o.y = w[0]*xu.y + w[1]*xd.y + w[2]*xl.y + w[3]*xc.w;
    o.z = w[4]*xu.z + w[5]*xd.z + w[6]*xc.x + w[7]*xr.x;
    o.w = w[4]*xu.w + w[5]*xd.w + w[6]*xc.y + w[7]*xr.y;
    if (m0) { o.x = xc.x; o.y = xc.y; }     // absorbing seeds
    if (m1) { o.z = xc.z; o.w = xc.w; }
    return o;
}

__device__ __forceinline__ void horiz(const float4* row, int tid, float4 xc,
                                      float2* xl, float2* xr) {
    const float2* r2 = (const float2*)row;
    *xl = (tid > 0) ? r2[2 * tid - 1] : make_float2(xc.x, xc.y);
    *xr = (tid < ROWP - 1) ? r2[2 * tid + 2] : make_float2(xc.z, xc.w);
}

// zero all flag slots: every launch self-contained (round-16-verified fix)
__global__ void rw_init_kernel(unsigned* __restrict__ flags) {
    int g = blockIdx.x * blockDim.x + threadIdx.x;
    if (g < FLAGS_N) flags[g] = 0u;
}

__launch_bounds__(TPB)
__global__ void rw_persist_kernel(const float* __restrict__ img,
                                  const int* __restrict__ seeds,
                                  float4* __restrict__ out4,   // d_out fp32, final only
                                  i32x2* __restrict__ parE,    // ws: fp16 x_{2m}, m even
                                  i32x2* __restrict__ parO,    // ws: fp16 x_{2m}, m odd
                                  unsigned* __restrict__ flags) {
    const int tid = threadIdx.x;
    const int blk = blockIdx.x;
    const int band = ((blk & 7) << 5) | (blk >> 3);   // XCD swizzle (perf only)
    const int i0 = band * 4;

    // slots 0..5: x rows i0-1..i0+4 (horizontal copies, fp32); 6..9: y rows
    __shared__ float4 srows[10][ROWP];                // 80 KB

    // ---- iteration-invariant weights + masks for rows i0-1..i0+4 ----
    float cfv[6][8];
    unsigned mb0 = 0, mb1 = 0;
    float4 s0, s1, s2, s3;                            // register-resident band (fp32)
    {
        const float2* img2 = (const float2*)img;
        const int2* seeds2 = (const int2*)seeds;
#pragma unroll
        for (int L = 0; L < 6; ++L) {
            const int g = min(max(i0 - 1 + L, 0), HH - 1);
            const int P = g * ROWP + tid;
            const int p = P * 2;
            const int j = p & 1023;
            const int uP = (g > 0) ? P - ROWP : P;
            const int dP = (g < HH - 1) ? P + ROWP : P;
            const int lp = (j > 0) ? p - 1 : p;
            const int rp = (j < 1022) ? p + 2 : p + 1;

            float2 cc = img2[P], iu = img2[uP], id = img2[dP];
            float il = img[lp], ir = img[rp];
            const float vU = (g > 0) ? 1.0f : 0.0f;
            const float vD = (g < HH - 1) ? 1.0f : 0.0f;
            const float vL = (j > 0) ? 1.0f : 0.0f;
            const float vR = (j < 1022) ? 1.0f : 0.0f;

            float w0u = wfun(cc.x, iu.x, vU), w0d = wfun(cc.x, id.x, vD);
            float w0l = wfun(cc.x, il, vL),   w0r = wfun(cc.x, cc.y, 1.0f);
            float rs0 = w0u + w0d + w0l + w0r;
            float inv0 = (rs0 > 0.0f) ? 1.0f / rs0 : 0.0f;
            float w1u = wfun(cc.y, iu.y, vU), w1d = wfun(cc.y, id.y, vD);
            float w1l = wfun(cc.y, cc.x, 1.0f), w1r = wfun(cc.y, ir, vR);
            float rs1 = w1u + w1d + w1l + w1r;
            float inv1 = (rs1 > 0.0f) ? 1.0f / rs1 : 0.0f;

            cfv[L][0] = w0u * inv0; cfv[L][1] = w0d * inv0;
            cfv[L][2] = w0l * inv0; cfv[L][3] = w0r * inv0;
            cfv[L][4] = w1u * inv1; cfv[L][5] = w1d * inv1;
            cfv[L][6] = w1l * inv1; cfv[L][7] = w1r * inv1;

            int2 s = seeds2[P];
            if (s.x > 0) mb0 |= 1u << L;
            if (s.y > 0) mb1 |= 1u << L;
            if (L >= 1 && L <= 4) {
                float4 v;
                v.x = (s.x == 1) ? 1.0f : 0.0f;
                v.y = (s.x == 2) ? 1.0f : 0.0f;
                v.z = (s.y == 1) ? 1.0f : 0.0f;
                v.w = (s.y == 2) ? 1.0f : 0.0f;
                if (L == 1) s0 = v; else if (L == 2) s1 = v;
                else if (L == 3) s2 = v; else s3 = v;
            }
        }
    }

    // ---- publish x0 (fp16) -> parE + seed LDS horizontal copies ----
    srows[1][tid] = s0; srows[2][tid] = s1;
    srows[3][tid] = s2; srows[4][tid] = s3;
    cst8(parE, (i0 + 0) * ROWP + tid, pack4(s0));
    cst8(parE, (i0 + 1) * ROWP + tid, pack4(s1));
    cst8(parE, (i0 + 2) * ROWP + tid, pack4(s2));
    cst8(parE, (i0 + 3) * ROWP + tid, pack4(s3));
    waitvm0();
    __syncthreads();               // LDS visible + publish drained
    if (tid == 0)
        __hip_atomic_store(&flags[band], TOKEN, __ATOMIC_RELAXED,
                           __HIP_MEMORY_SCOPE_AGENT);

    const int gU2 = max(i0 - 2, 0), gU1 = max(i0 - 1, 0);
    const int gD0 = min(i0 + 4, HH - 1), gD1 = min(i0 + 5, HH - 1);

    for (int m = 0; m < NSYNC; ++m) {
        // ---- poll neighbors' x_{2m} flags (two waves in parallel, no backoff:
        // poll period = natural ~L3 load latency; relaxed loads, no cache ops) ----
        if (tid == 0 && band > 0) {
            int guard = 0;
            while (__hip_atomic_load(&flags[m * NBLK + band - 1], __ATOMIC_RELAXED,
                                     __HIP_MEMORY_SCOPE_AGENT) != TOKEN) {
                if (++guard > (1 << 22)) break;
            }
        }
        if (tid == 64 && band < NBLK - 1) {
            int guard = 0;
            while (__hip_atomic_load(&flags[m * NBLK + band + 1], __ATOMIC_RELAXED,
                                     __HIP_MEMORY_SCOPE_AGENT) != TOKEN) {
                if (++guard > (1 << 22)) break;
            }
        }
        __syncthreads();                              // [A]
        asm volatile("" ::: "memory");

        const i32x2* pin = (m & 1) ? parO : parE;

        // ---- issue 2-deep ghost row loads (coherent fp16 8B) ----
        i32x2 rA = cld8(pin, gU2 * ROWP + tid);       // row i0-2
        i32x2 rB = cld8(pin, gU1 * ROWP + tid);       // row i0-1
        i32x2 rC = cld8(pin, gD0 * ROWP + tid);       // row i0+4
        i32x2 rD = cld8(pin, gD1 * ROWP + tid);       // row i0+5

        // ---- step 1 interior rows (no ghost dep) while loads fly ----
        float2 xl, xr;
        horiz(&srows[2][0], tid, s1, &xl, &xr);
        float4 y2 = stepr(cfv[2], (mb0 >> 2) & 1, (mb1 >> 2) & 1, s1, s0, s2, xl, xr);
        horiz(&srows[3][0], tid, s2, &xl, &xr);
        float4 y3 = stepr(cfv[3], (mb0 >> 3) & 1, (mb1 >> 3) & 1, s2, s1, s3, xl, xr);
        srows[7][tid] = y2;
        srows[8][tid] = y3;

        wait4(rA, rB, rC, rD);                        // loads landed; deps tied
        float4 vU2 = unpack4(rA);
        float4 vU1 = unpack4(rB);
        float4 vD0 = unpack4(rC);
        float4 vD1 = unpack4(rD);
        srows[0][tid] = vU1;
        srows[5][tid] = vD0;
        __syncthreads();                              // [B]

        // ---- step 1 ghost-dependent rows ----
        horiz(&srows[0][0], tid, vU1, &xl, &xr);
        float4 y0 = stepr(cfv[0], (mb0 >> 0) & 1, (mb1 >> 0) & 1, vU1, vU2, s0, xl, xr);
        horiz(&srows[1][0], tid, s0, &xl, &xr);
        float4 y1 = stepr(cfv[1], (mb0 >> 1) & 1, (mb1 >> 1) & 1, s0, vU1, s1, xl, xr);
        horiz(&srows[4][0], tid, s3, &xl, &xr);
        float4 y4 = stepr(cfv[4], (mb0 >> 4) & 1, (mb1 >> 4) & 1, s3, s2, vD0, xl, xr);
        horiz(&srows[5][0], tid, vD0, &xl, &xr);
        float4 y5 = stepr(cfv[5], (mb0 >> 5) & 1, (mb1 >> 5) & 1, vD0, s3, vD1, xl, xr);
        srows[6][tid] = y1;
        srows[9][tid] = y4;
        __syncthreads();                              // [C]

        // ---- step 2, own rows; publish each o row the moment it exists ----
        i32x2* pout = (m & 1) ? parE : parO;
        const bool last = (m == NSYNC - 1);

        horiz(&srows[6][0], tid, y1, &xl, &xr);
        float4 o0 = stepr(cfv[1], (mb0 >> 1) & 1, (mb1 >> 1) & 1, y1, y0, y2, xl, xr);
        if (!last) cst8(pout, (i0 + 0) * ROWP + tid, pack4(o0));
        horiz(&srows[7][0], tid, y2, &xl, &xr);
        float4 o1 = stepr(cfv[2], (mb0 >> 2) & 1, (mb1 >> 2) & 1, y2, y1, y3, xl, xr);
        if (!last) cst8(pout, (i0 + 1) * ROWP + tid, pack4(o1));
        horiz(&srows[8][0], tid, y3, &xl, &xr);
        float4 o2 = stepr(cfv[3], (mb0 >> 3) & 1, (mb1 >> 3) & 1, y3, y2, y4, xl, xr);
        if (!last) cst8(pout, (i0 + 2) * ROWP + tid, pack4(o2));
        horiz(&srows[9][0], tid, y4, &xl, &xr);
        float4 o3 = stepr(cfv[4], (mb0 >> 4) & 1, (mb1 >> 4) & 1, y4, y3, y5, xl, xr);
        if (!last) cst8(pout, (i0 + 3) * ROWP + tid, pack4(o3));

        if (last) {
            // x_100 -> d_out fp32 (never read by any block: race-free)
            out4[(i0 + 0) * ROWP + tid] = o0;
            out4[(i0 + 1) * ROWP + tid] = o1;
            out4[(i0 + 2) * ROWP + tid] = o2;
            out4[(i0 + 3) * ROWP + tid] = o3;
            break;
        }

        waitvm0();                                    // each wave drains publishes
        __syncthreads();                              // [D] all waves drained
        if (tid == 0)
            __hip_atomic_store(&flags[(m + 1) * NBLK + band], TOKEN,
                               __ATOMIC_RELAXED, __HIP_MEMORY_SCOPE_AGENT);

        // ---- off-chain: LDS writeback + register rotation (hidden under the
        // neighbors' poll window; made visible by next sync's [A] barrier) ----
        srows[1][tid] = o0; srows[2][tid] = o1;
        srows[3][tid] = o2; srows[4][tid] = o3;
        s0 = o0; s1 = o1; s2 = o2; s3 = o3;
    }
}

extern "C" void kernel_launch(void* const* d_in, const int* in_sizes, int n_in,
                              void* d_out, int out_size, void* d_ws, size_t ws_size,
                              hipStream_t stream) {
    const float* img = (const float*)d_in[0];
    const int* seeds = (const int*)d_in[1];

    float4* out4 = (float4*)d_out;                              // fp32 final only
    char* ws = (char*)d_ws;
    i32x2* parE = (i32x2*)ws;                                   // 4 MB fp16 even parity
    i32x2* parO = (i32x2*)(ws + 4ull * 1024 * 1024);            // 4 MB fp16 odd parity
    unsigned* flags = (unsigned*)(ws + 8ull * 1024 * 1024);     // 51.2 KB token slots

    rw_init_kernel<<<(FLAGS_N + 255) / 256, 256, 0, stream>>>(flags);
    rw_persist_kernel<<<NBLK, TPB, 0, stream>>>(img, seeds, out4, parE, parO, flags);
}